// Round 1
// baseline (210.541 us; speedup 1.0000x reference)
//
#include <hip/hip_runtime.h>
#include <stdint.h>

typedef unsigned short u16;
typedef __attribute__((ext_vector_type(8))) short bf16x8;
typedef __attribute__((ext_vector_type(4))) float f32x4;

__device__ __forceinline__ u16 f2bf(float f){
  union { float f; uint32_t u; } v; v.f = f;
  uint32_t u = v.u;
  u += 0x7FFFu + ((u >> 16) & 1u);
  return (u16)(u >> 16);
}

__device__ __forceinline__ f32x4 mfma_bf16(bf16x8 a, bf16x8 b, f32x4 c){
  return __builtin_amdgcn_mfma_f32_16x16x32_bf16(a, b, c, 0, 0, 0);
}

// ---------------- cast x (fp32 -> bf16), 4 elems/thread ----------------
__global__ __launch_bounds__(256) void cast_x_k(const float* __restrict__ x,
                                                u16* __restrict__ xb, int n4){
  int i = blockIdx.x*256 + threadIdx.x;
  if (i >= n4) return;
  float4 v = reinterpret_cast<const float4*>(x)[i];
  uint2 o;
  o.x = (uint32_t)f2bf(v.x) | ((uint32_t)f2bf(v.y) << 16);
  o.y = (uint32_t)f2bf(v.z) | ((uint32_t)f2bf(v.w) << 16);
  reinterpret_cast<uint2*>(xb)[i] = o;
}

// ---------------- transpose+cast: fp32 [R][C] -> bf16 [C][R] ----------------
__global__ __launch_bounds__(256) void transpose_cast_k(const float* __restrict__ in,
                                                        u16* __restrict__ out,
                                                        int R, int C){
  __shared__ u16 tile[64][66];
  int c0 = blockIdx.x*64, r0 = blockIdx.y*64;
  int tc = threadIdx.x & 63, t4 = threadIdx.x >> 6;
  #pragma unroll
  for (int i=0;i<16;i++){ int r = t4 + i*4; tile[r][tc] = f2bf(in[(size_t)(r0+r)*C + c0 + tc]); }
  __syncthreads();
  #pragma unroll
  for (int i=0;i<16;i++){ int cc = t4 + i*4; out[(size_t)(c0+cc)*R + r0 + tc] = tile[tc][cc]; }
}

// ---------------- transpose V per (b,h): bf16 [2048][64] -> [64][2048] ----------------
__global__ __launch_bounds__(256) void transpose_v_k(const u16* __restrict__ v,
                                                     u16* __restrict__ vt){
  __shared__ u16 tile[64][66];
  int r0 = blockIdx.x*64;
  size_t base = (size_t)blockIdx.y * 131072;  // 2048*64
  int tc = threadIdx.x & 63, t4 = threadIdx.x >> 6;
  #pragma unroll
  for (int i=0;i<16;i++){ int r = t4 + i*4; tile[r][tc] = v[base + (size_t)(r0+r)*64 + tc]; }
  __syncthreads();
  #pragma unroll
  for (int i=0;i<16;i++){ int d = t4 + i*4; vt[base + (size_t)d*2048 + r0 + tc] = tile[tc][d]; }
}

// ---------------- bf16 MFMA GEMM: C[M][N] = A[M][K] * Bt[N][K]^T + bias ----------------
// mode 0: fp32 out to fo.  mode 1: scatter bf16 into q/k/v [B*H][T][64].
#define LDP 40   // padded LDS row stride (shorts); keeps 16B chunk alignment

__global__ __launch_bounds__(256) void gemm_bf16_k(
    const u16* __restrict__ A, const u16* __restrict__ Bt,
    int M, int N, int K, const float* __restrict__ bias, int mode,
    u16* __restrict__ qo, u16* __restrict__ ko, u16* __restrict__ vo,
    float* __restrict__ fo)
{
  __shared__ u16 As[128*LDP];
  __shared__ u16 Bs[128*LDP];
  const int m0 = blockIdx.y*128, n0 = blockIdx.x*128;
  const int tid = threadIdx.x, lane = tid & 63, wid = tid >> 6;
  const int lr = lane & 15, lg = lane >> 4;
  const int wr = wid >> 1, wc = wid & 1;
  f32x4 acc[4][4] = {};
  const int nk = K >> 5;
  for (int kk = 0; kk < nk; ++kk){
    #pragma unroll
    for (int s = 0; s < 2; ++s){
      int ci = tid + 256*s;
      int row = ci >> 2, ch = ci & 3;
      *(uint4*)&As[row*LDP + ch*8] = *(const uint4*)&A[(size_t)(m0+row)*K + kk*32 + ch*8];
      *(uint4*)&Bs[row*LDP + ch*8] = *(const uint4*)&Bt[(size_t)(n0+row)*K + kk*32 + ch*8];
    }
    __syncthreads();
    bf16x8 af[4], bfr[4];
    #pragma unroll
    for (int m=0;m<4;m++) af[m] = *(const bf16x8*)&As[(wr*64 + m*16 + lr)*LDP + lg*8];
    #pragma unroll
    for (int n=0;n<4;n++) bfr[n] = *(const bf16x8*)&Bs[(wc*64 + n*16 + lr)*LDP + lg*8];
    #pragma unroll
    for (int m=0;m<4;m++)
      #pragma unroll
      for (int n=0;n<4;n++)
        acc[m][n] = mfma_bf16(af[m], bfr[n], acc[m][n]);
    __syncthreads();
  }
  if (mode == 0){
    #pragma unroll
    for (int m=0;m<4;m++)
      #pragma unroll
      for (int n=0;n<4;n++){
        int gn = n0 + wc*64 + n*16 + lr;
        float bv = bias[gn];
        #pragma unroll
        for (int r=0;r<4;r++){
          int gm = m0 + wr*64 + m*16 + lg*4 + r;
          fo[(size_t)gm*N + gn] = acc[m][n][r] + bv;
        }
      }
  } else {
    int which = n0 / 768;               // 128 | 768 -> uniform per block
    u16* dst = (which==0) ? qo : (which==1) ? ko : vo;
    #pragma unroll
    for (int m=0;m<4;m++)
      #pragma unroll
      for (int n=0;n<4;n++){
        int gn = n0 + wc*64 + n*16 + lr;
        float bv = bias[gn];
        int cn = gn - which*768;
        int h = cn >> 6, d = cn & 63;
        #pragma unroll
        for (int r=0;r<4;r++){
          int gm = m0 + wr*64 + m*16 + lg*4 + r;
          int b = gm >> 11, t = gm & 2047;
          dst[(size_t)((b*12 + h)*2048 + t)*64 + d] = f2bf(acc[m][n][r] + bv);
        }
      }
  }
}

// ---------------- causal flash attention ----------------
// grid: (T/64, B*H). 4 waves x 16 q-rows. KV tiles of 32 keys.
__global__ __launch_bounds__(256) void attn_k(
    const u16* __restrict__ q, const u16* __restrict__ k,
    const u16* __restrict__ vt, u16* __restrict__ y)
{
  __shared__ u16 Kls[32*72];     // [key][hd], rows padded to 72 shorts
  __shared__ u16 Vls[64*40];     // [d][key], rows padded to 40 shorts
  __shared__ u16 Pls[4][16*40];  // per-wave P tile [qrow][key]
  const int bh = blockIdx.y, q0 = blockIdx.x*64;
  const int b = bh/12, h = bh - b*12;
  const size_t base = (size_t)bh * 131072;
  const int tid = threadIdx.x, lane = tid & 63, wid = tid >> 6;
  const int lr = lane & 15, lg = lane >> 4;
  const int qrow = q0 + wid*16;
  bf16x8 qf[2];
  #pragma unroll
  for (int kb=0;kb<2;kb++)
    qf[kb] = *(const bf16x8*)&q[base + (size_t)(qrow+lr)*64 + kb*32 + lg*8];
  f32x4 yacc[4] = {};
  float m_r[4], l_r[4];
  #pragma unroll
  for (int r=0;r<4;r++){ m_r[r] = -1e30f; l_r[r] = 0.f; }
  const int nt = (q0 + 64) >> 5;
  const int srow = tid >> 3, sch = tid & 7;   // K staging: 32 rows x 8 chunks
  const int vrow = tid >> 2, vch = tid & 3;   // V staging: 64 rows x 4 chunks
  for (int t=0;t<nt;++t){
    const int k0 = t*32;
    *(uint4*)&Kls[srow*72 + sch*8] = *(const uint4*)&k[base + (size_t)(k0+srow)*64 + sch*8];
    *(uint4*)&Vls[vrow*40 + vch*8] = *(const uint4*)&vt[base + (size_t)vrow*2048 + k0 + vch*8];
    __syncthreads();
    if (k0 <= qrow + 15){            // wave-uniform: any of this wave's rows see this tile
      f32x4 s[2] = {};
      #pragma unroll
      for (int nb=0;nb<2;nb++)
        #pragma unroll
        for (int kb=0;kb<2;kb++){
          bf16x8 kf = *(const bf16x8*)&Kls[(nb*16+lr)*72 + kb*32 + lg*8];
          s[nb] = mfma_bf16(qf[kb], kf, s[nb]);
        }
      u16* Pw = Pls[wid];
      #pragma unroll
      for (int r=0;r<4;r++){
        int qg = qrow + lg*4 + r;
        float s0 = s[0][r]*0.125f; if (k0 + lr      > qg) s0 = -1e30f;
        float s1 = s[1][r]*0.125f; if (k0 + 16 + lr > qg) s1 = -1e30f;
        float mv = fmaxf(s0, s1);
        mv = fmaxf(mv, __shfl_xor(mv, 1));
        mv = fmaxf(mv, __shfl_xor(mv, 2));
        mv = fmaxf(mv, __shfl_xor(mv, 4));
        mv = fmaxf(mv, __shfl_xor(mv, 8));
        float nm = fmaxf(m_r[r], mv);
        float alpha = __expf(m_r[r] - nm);
        float p0 = __expf(s0 - nm);
        float p1 = __expf(s1 - nm);
        float sum = p0 + p1;
        sum += __shfl_xor(sum, 1);
        sum += __shfl_xor(sum, 2);
        sum += __shfl_xor(sum, 4);
        sum += __shfl_xor(sum, 8);
        l_r[r] = l_r[r]*alpha + sum;
        m_r[r] = nm;
        yacc[0][r] *= alpha; yacc[1][r] *= alpha;
        yacc[2][r] *= alpha; yacc[3][r] *= alpha;
        Pw[(lg*4+r)*40 + lr]      = f2bf(p0);
        Pw[(lg*4+r)*40 + 16 + lr] = f2bf(p1);
      }
      // same-wave cross-lane LDS dependency: drain LDS then fence the scheduler
      asm volatile("s_waitcnt lgkmcnt(0)" ::: "memory");
      __builtin_amdgcn_sched_barrier(0);
      bf16x8 pf = *(const bf16x8*)&Pw[lr*40 + lg*8];
      #pragma unroll
      for (int n=0;n<4;n++){
        bf16x8 vf = *(const bf16x8*)&Vls[(n*16+lr)*40 + lg*8];
        yacc[n] = mfma_bf16(pf, vf, yacc[n]);
      }
    }
    __syncthreads();
  }
  #pragma unroll
  for (int n=0;n<4;n++)
    #pragma unroll
    for (int r=0;r<4;r++){
      int qg = qrow + lg*4 + r;
      int col = h*64 + n*16 + lr;
      y[(size_t)(b*2048 + qg)*768 + col] = f2bf(yacc[n][r] / l_r[r]);
    }
}

extern "C" void kernel_launch(void* const* d_in, const int* in_sizes, int n_in,
                              void* d_out, int out_size, void* d_ws, size_t ws_size,
                              hipStream_t stream)
{
  const float* x  = (const float*)d_in[0];   // [2,2048,768]
  const float* Wa = (const float*)d_in[1];   // [768,2304]
  const float* ba = (const float*)d_in[2];   // [2304]
  const float* Wp = (const float*)d_in[3];   // [768,768]
  const float* bp = (const float*)d_in[4];   // [768]
  float* out = (float*)d_out;                // [2,2048,768] fp32
  char* ws = (char*)d_ws;
  u16* xb  = (u16*)(ws + 0);         // x bf16          [4096][768]
  u16* wt  = (u16*)(ws + 6291456);   // W_attn^T bf16   [2304][768]
  u16* wpt = (u16*)(ws + 9830400);   // W_proj^T bf16   [768][768]
  u16* qb  = (u16*)(ws + 11010048);  // q bf16          [24][2048][64]
  u16* kb  = (u16*)(ws + 17301504);  // k bf16          [24][2048][64]
  u16* vb  = (u16*)(ws + 23592960);  // v bf16          [24][2048][64]
  u16* vtb = (u16*)(ws + 29884416);  // v^T bf16        [24][64][2048]
  u16* yb  = (u16*)(ws + 36175872);  // attn out bf16   [4096][768]

  cast_x_k<<<3072, 256, 0, stream>>>(x, xb, 786432);
  transpose_cast_k<<<dim3(36,12), 256, 0, stream>>>(Wa, wt, 768, 2304);
  transpose_cast_k<<<dim3(12,12), 256, 0, stream>>>(Wp, wpt, 768, 768);
  gemm_bf16_k<<<dim3(18,32), 256, 0, stream>>>(xb, wt, 4096, 2304, 768, ba, 1,
                                               qb, kb, vb, nullptr);
  transpose_v_k<<<dim3(32,24), 256, 0, stream>>>(vb, vtb);
  attn_k<<<dim3(32,24), 256, 0, stream>>>(qb, kb, vtb, yb);
  gemm_bf16_k<<<dim3(6,32), 256, 0, stream>>>(yb, wpt, 4096, 768, 768, bp, 0,
                                              nullptr, nullptr, nullptr, out);
}

// Round 2
// 190.315 us; speedup vs baseline: 1.1063x; 1.1063x over previous
//
#include <hip/hip_runtime.h>
#include <stdint.h>

typedef unsigned short u16;
typedef __attribute__((ext_vector_type(8))) short bf16x8;
typedef __attribute__((ext_vector_type(4))) float f32x4;

__device__ __forceinline__ u16 f2bf(float f){
  union { float f; uint32_t u; } v; v.f = f;
  uint32_t u = v.u;
  u += 0x7FFFu + ((u >> 16) & 1u);
  return (u16)(u >> 16);
}

__device__ __forceinline__ float fexp2(float x){
#if __has_builtin(__builtin_amdgcn_exp2f)
  return __builtin_amdgcn_exp2f(x);
#else
  return exp2f(x);
#endif
}

__device__ __forceinline__ uint32_t cvtpk_bf16(float lo, float hi){
  uint32_t d;
  asm("v_cvt_pk_bf16_f32 %0, %1, %2" : "=v"(d) : "v"(lo), "v"(hi));
  return d;
}

__device__ __forceinline__ f32x4 mfma_bf16(bf16x8 a, bf16x8 b, f32x4 c){
  return __builtin_amdgcn_mfma_f32_16x16x32_bf16(a, b, c, 0, 0, 0);
}

// 0.125 (1/sqrt(64)) * log2(e) -- folded into Q at the QKV epilogue
#define QSCALE 0.1803368801111244f

// ---------------- cast x (fp32 -> bf16), 4 elems/thread ----------------
__global__ __launch_bounds__(256) void cast_x_k(const float* __restrict__ x,
                                                u16* __restrict__ xb, int n4){
  int i = blockIdx.x*256 + threadIdx.x;
  if (i >= n4) return;
  float4 v = reinterpret_cast<const float4*>(x)[i];
  uint2 o;
  o.x = (uint32_t)f2bf(v.x) | ((uint32_t)f2bf(v.y) << 16);
  o.y = (uint32_t)f2bf(v.z) | ((uint32_t)f2bf(v.w) << 16);
  reinterpret_cast<uint2*>(xb)[i] = o;
}

// ---------------- transpose+cast: fp32 [R][C] -> bf16 [C][R] ----------------
__global__ __launch_bounds__(256) void transpose_cast_k(const float* __restrict__ in,
                                                        u16* __restrict__ out,
                                                        int R, int C){
  __shared__ u16 tile[64][66];
  int c0 = blockIdx.x*64, r0 = blockIdx.y*64;
  int tc = threadIdx.x & 63, t4 = threadIdx.x >> 6;
  #pragma unroll
  for (int i=0;i<16;i++){ int r = t4 + i*4; tile[r][tc] = f2bf(in[(size_t)(r0+r)*C + c0 + tc]); }
  __syncthreads();
  #pragma unroll
  for (int i=0;i<16;i++){ int cc = t4 + i*4; out[(size_t)(c0+cc)*R + r0 + tc] = tile[tc][cc]; }
}

// ---------------- transpose V per (b,h): bf16 [2048][64] -> [64][2048] ----------------
__global__ __launch_bounds__(256) void transpose_v_k(const u16* __restrict__ v,
                                                     u16* __restrict__ vt){
  __shared__ u16 tile[64][66];
  int r0 = blockIdx.x*64;
  size_t base = (size_t)blockIdx.y * 131072;  // 2048*64
  int tc = threadIdx.x & 63, t4 = threadIdx.x >> 6;
  #pragma unroll
  for (int i=0;i<16;i++){ int r = t4 + i*4; tile[r][tc] = v[base + (size_t)(r0+r)*64 + tc]; }
  __syncthreads();
  #pragma unroll
  for (int i=0;i<16;i++){ int d = t4 + i*4; vt[base + (size_t)d*2048 + r0 + tc] = tile[tc][d]; }
}

// ---------------- bf16 MFMA GEMM: C[M][N] = A[M][K] * Bt[N][K]^T + bias ----------------
// mode 0: fp32 out to fo.  mode 1: scatter bf16 into q/k/v [B*H][T][64] (q pre-scaled).
#define LDP 40   // padded LDS row stride (shorts)

__global__ __launch_bounds__(256) void gemm_bf16_k(
    const u16* __restrict__ A, const u16* __restrict__ Bt,
    int M, int N, int K, const float* __restrict__ bias, int mode,
    u16* __restrict__ qo, u16* __restrict__ ko, u16* __restrict__ vo,
    float* __restrict__ fo)
{
  __shared__ u16 As[128*LDP];
  __shared__ u16 Bs[128*LDP];
  const int m0 = blockIdx.y*128, n0 = blockIdx.x*128;
  const int tid = threadIdx.x, lane = tid & 63, wid = tid >> 6;
  const int lr = lane & 15, lg = lane >> 4;
  const int wr = wid >> 1, wc = wid & 1;
  f32x4 acc[4][4] = {};
  const int nk = K >> 5;
  for (int kk = 0; kk < nk; ++kk){
    #pragma unroll
    for (int s = 0; s < 2; ++s){
      int ci = tid + 256*s;
      int row = ci >> 2, ch = ci & 3;
      *(uint4*)&As[row*LDP + ch*8] = *(const uint4*)&A[(size_t)(m0+row)*K + kk*32 + ch*8];
      *(uint4*)&Bs[row*LDP + ch*8] = *(const uint4*)&Bt[(size_t)(n0+row)*K + kk*32 + ch*8];
    }
    __syncthreads();
    bf16x8 af[4], bfr[4];
    #pragma unroll
    for (int m=0;m<4;m++) af[m] = *(const bf16x8*)&As[(wr*64 + m*16 + lr)*LDP + lg*8];
    #pragma unroll
    for (int n=0;n<4;n++) bfr[n] = *(const bf16x8*)&Bs[(wc*64 + n*16 + lr)*LDP + lg*8];
    #pragma unroll
    for (int m=0;m<4;m++)
      #pragma unroll
      for (int n=0;n<4;n++)
        acc[m][n] = mfma_bf16(af[m], bfr[n], acc[m][n]);
    __syncthreads();
  }
  if (mode == 0){
    #pragma unroll
    for (int m=0;m<4;m++)
      #pragma unroll
      for (int n=0;n<4;n++){
        int gn = n0 + wc*64 + n*16 + lr;
        float bv = bias[gn];
        #pragma unroll
        for (int r=0;r<4;r++){
          int gm = m0 + wr*64 + m*16 + lg*4 + r;
          fo[(size_t)gm*N + gn] = acc[m][n][r] + bv;
        }
      }
  } else {
    int which = n0 / 768;               // 0=q 1=k 2=v, uniform per block
    u16* dst = (which==0) ? qo : (which==1) ? ko : vo;
    float sc = (which==0) ? QSCALE : 1.0f;
    #pragma unroll
    for (int m=0;m<4;m++)
      #pragma unroll
      for (int n=0;n<4;n++){
        int gn = n0 + wc*64 + n*16 + lr;
        float bv = bias[gn];
        int cn = gn - which*768;
        int h = cn >> 6, d = cn & 63;
        #pragma unroll
        for (int r=0;r<4;r++){
          int gm = m0 + wr*64 + m*16 + lg*4 + r;
          int b = gm >> 11, t = gm & 2047;
          dst[(size_t)((b*12 + h)*2048 + t)*64 + d] = f2bf((acc[m][n][r] + bv)*sc);
        }
      }
  }
}

// ---------------- causal flash attention (swapped-operand, in-register softmax) -------
// grid: (32, B*H) with q0 descending (heavy blocks first). 4 waves x 16 q-rows.
// KV tiles of 64 keys, double-buffered LDS, one barrier per tile.
// Swapped QK^T: S^T = mfma(K, Q) -> lane holds scores for q = lane&15, keys in regs.
// K rows stored pi-permuted so each lane's 16 scores are exactly its PV B-frag slices.
// Transposed PV: y^T = mfma(V^T, P) -> y cols = q = lane&15 (per-lane m/l/rescale).
__global__ __launch_bounds__(256) void attn_k(
    const u16* __restrict__ qp, const u16* __restrict__ kp,
    const u16* __restrict__ vtp, u16* __restrict__ yp)
{
  __shared__ u16 Kls[2][64*64];
  __shared__ u16 Vls[2][64*64];
  const int bh = blockIdx.y;
  const int q0 = (31 - (int)blockIdx.x) * 64;
  const int b = bh / 12, h = bh - b*12;
  const size_t base = (size_t)bh * 131072;
  const int tid = threadIdx.x, lane = tid & 63, wid = tid >> 6;
  const int lr = lane & 15, lg = lane >> 4;
  const int q0w = q0 + wid*16;
  const int qg = q0w + lr;

  // Q fragments (Q pre-scaled by QSCALE in the QKV epilogue)
  bf16x8 qf[2];
  #pragma unroll
  for (int kb=0;kb<2;kb++)
    qf[kb] = *(const bf16x8*)&qp[base + (size_t)qg*64 + kb*32 + lg*8];

  f32x4 yacc[4] = {};
  float m2 = -1e4f, l = 0.f;

  const int nt = (q0 >> 6) + 1;
  const int rho0 = tid >> 3, c0 = tid & 7;

  uint4 kreg[2], vreg[2];
  auto pi_perm = [](int rho){
    return ((rho>>4)&1)*32 + ((rho>>2)&3)*8 + ((rho>>5)&1)*4 + (rho&3);
  };
  auto load_tile = [&](int k0){
    #pragma unroll
    for (int i=0;i<2;i++){
      int rho = rho0 + i*32;
      int key = pi_perm(rho);
      int cg = (c0 ^ (rho & 7)) * 8;   // XOR-swizzled source chunk
      kreg[i] = *(const uint4*)&kp[base + (size_t)(k0+key)*64 + cg];
      vreg[i] = *(const uint4*)&vtp[base + (size_t)rho*2048 + k0 + cg];
    }
  };
  auto write_tile = [&](int buf){
    #pragma unroll
    for (int i=0;i<2;i++){
      int rho = rho0 + i*32;
      *(uint4*)&Kls[buf][rho*64 + c0*8] = kreg[i];
      *(uint4*)&Vls[buf][rho*64 + c0*8] = vreg[i];
    }
  };

  load_tile(0);
  write_tile(0);
  __syncthreads();

  for (int t=0; t<nt; ++t){
    const int k0 = t*64;
    const int cur = t & 1;
    if (t+1 < nt) load_tile((t+1)*64);

    // ---- QK^T (swapped): s[nb][r] = S[key = k0 + pi(nb*16+lg*4+r)][q = qg]
    f32x4 s[4] = {};
    #pragma unroll
    for (int kb=0;kb<2;kb++)
      #pragma unroll
      for (int nb=0;nb<4;nb++){
        bf16x8 kf = *(const bf16x8*)&Kls[cur][(nb*16+lr)*64 + (((kb*4+lg)^(lr&7))*8)];
        s[nb] = mfma_bf16(kf, qf[kb], s[nb]);
      }

    // ---- causal mask (only diagonal tile needs it)
    if (k0 + 63 > q0w){
      #pragma unroll
      for (int nb=0;nb<4;nb++){
        int kb0 = k0 + (nb&1)*32 + ((nb>>1)&1)*4 + lg*8;
        #pragma unroll
        for (int r=0;r<4;r++)
          if (kb0 + r > qg) s[nb][r] = -1e30f;
      }
    }

    // ---- tile max (in-lane over 16, then across the 4 lg-lanes of this q-row)
    float tmax = s[0][0];
    #pragma unroll
    for (int nb=0;nb<4;nb++)
      #pragma unroll
      for (int r=0;r<4;r++) tmax = fmaxf(tmax, s[nb][r]);
    tmax = fmaxf(tmax, __shfl_xor(tmax, 16));
    tmax = fmaxf(tmax, __shfl_xor(tmax, 32));

    // ---- deferred rescale (T13): only when max grows past threshold (rare)
    if (!__all(tmax <= m2 + 11.5f)){
      float m2n = fmaxf(m2, tmax);
      float al = fexp2(m2 - m2n);
      l *= al;
      #pragma unroll
      for (int n=0;n<4;n++) yacc[n] *= al;
      m2 = m2n;
    }

    // ---- p = 2^(s - m2), partial row-sum kept per lane
    float lsum = 0.f;
    #pragma unroll
    for (int nb=0;nb<4;nb++)
      #pragma unroll
      for (int r=0;r<4;r++){
        float p = fexp2(s[nb][r] - m2);
        s[nb][r] = p;
        lsum += p;
      }
    l += lsum;

    // ---- pack P to bf16 in-register (keys land exactly in B-frag order)
    uint32_t pk8[8];
    #pragma unroll
    for (int nb=0;nb<4;nb++){
      pk8[nb*2]   = cvtpk_bf16(s[nb][0], s[nb][1]);
      pk8[nb*2+1] = cvtpk_bf16(s[nb][2], s[nb][3]);
    }

    // ---- PV (transposed): yacc[n] rows = d = n*16+lg*4+r, col = q = lane&15
    #pragma unroll
    for (int kc=0;kc<2;kc++){
      union { uint32_t u[4]; bf16x8 v; } pb;
      pb.u[0] = pk8[kc*2];   pb.u[1] = pk8[kc*2+1];
      pb.u[2] = pk8[kc*2+4]; pb.u[3] = pk8[kc*2+5];
      #pragma unroll
      for (int n=0;n<4;n++){
        bf16x8 vf = *(const bf16x8*)&Vls[cur][(n*16+lr)*64 + (((kc*4+lg)^(lr&7))*8)];
        yacc[n] = mfma_bf16(vf, pb.v, yacc[n]);
      }
    }

    if (t+1 < nt) write_tile((t+1) & 1);
    __syncthreads();
  }

  // ---- epilogue: total l across the 4 lg-lanes of each q-row, write y^T
  l += __shfl_xor(l, 16);
  l += __shfl_xor(l, 32);
  float inv = 1.0f / l;
  #pragma unroll
  for (int n=0;n<4;n++){
    uint2 o;
    o.x = cvtpk_bf16(yacc[n][0]*inv, yacc[n][1]*inv);
    o.y = cvtpk_bf16(yacc[n][2]*inv, yacc[n][3]*inv);
    *(uint2*)&yp[(size_t)(b*2048 + qg)*768 + h*64 + n*16 + lg*4] = o;
  }
}

extern "C" void kernel_launch(void* const* d_in, const int* in_sizes, int n_in,
                              void* d_out, int out_size, void* d_ws, size_t ws_size,
                              hipStream_t stream)
{
  const float* x  = (const float*)d_in[0];   // [2,2048,768]
  const float* Wa = (const float*)d_in[1];   // [768,2304]
  const float* ba = (const float*)d_in[2];   // [2304]
  const float* Wp = (const float*)d_in[3];   // [768,768]
  const float* bp = (const float*)d_in[4];   // [768]
  float* out = (float*)d_out;                // [2,2048,768] fp32
  char* ws = (char*)d_ws;
  u16* xb  = (u16*)(ws + 0);         // x bf16          [4096][768]
  u16* wt  = (u16*)(ws + 6291456);   // W_attn^T bf16   [2304][768]
  u16* wpt = (u16*)(ws + 9830400);   // W_proj^T bf16   [768][768]
  u16* qb  = (u16*)(ws + 11010048);  // q bf16 (scaled) [24][2048][64]
  u16* kb  = (u16*)(ws + 17301504);  // k bf16          [24][2048][64]
  u16* vb  = (u16*)(ws + 23592960);  // v bf16          [24][2048][64]
  u16* vtb = (u16*)(ws + 29884416);  // v^T bf16        [24][64][2048]
  u16* yb  = (u16*)(ws + 36175872);  // attn out bf16   [4096][768]

  cast_x_k<<<3072, 256, 0, stream>>>(x, xb, 786432);
  transpose_cast_k<<<dim3(36,12), 256, 0, stream>>>(Wa, wt, 768, 2304);
  transpose_cast_k<<<dim3(12,12), 256, 0, stream>>>(Wp, wpt, 768, 768);
  gemm_bf16_k<<<dim3(18,32), 256, 0, stream>>>(xb, wt, 4096, 2304, 768, ba, 1,
                                               qb, kb, vb, nullptr);
  transpose_v_k<<<dim3(32,24), 256, 0, stream>>>(vb, vtb);
  attn_k<<<dim3(32,24), 256, 0, stream>>>(qb, kb, vtb, yb);
  gemm_bf16_k<<<dim3(6,32), 256, 0, stream>>>(yb, wpt, 4096, 768, 768, bp, 0,
                                              nullptr, nullptr, nullptr, out);
}